// Round 9
// baseline (587.369 us; speedup 1.0000x reference)
//
#include <hip/hip_runtime.h>

#define DD 64
#define EPB 1024  // edges per block in fill pipeline
#define NREP 8    // gcur replicas (anti-serialization)

typedef float f32x4 __attribute__((ext_vector_type(4)));
typedef __bf16 bf16x8 __attribute__((ext_vector_type(8)));

__device__ __forceinline__ unsigned enc_f32(float x) {
  unsigned u = __float_as_uint(x);
  return (u & 0x80000000u) ? ~u : (u | 0x80000000u);
}
__device__ __forceinline__ float dec_f32(unsigned k) {
  return (k & 0x80000000u) ? __uint_as_float(k ^ 0x80000000u)
                           : __uint_as_float(~k);
}
__device__ __forceinline__ unsigned f2bf(float x) {
  unsigned u = __float_as_uint(x);
  return (u + 0x7fffu + ((u >> 16) & 1u)) >> 16;
}
__device__ __forceinline__ void unpack8(const uint4 raw, float* v) {
  v[0] = __uint_as_float(raw.x << 16);
  v[1] = __uint_as_float(raw.x & 0xffff0000u);
  v[2] = __uint_as_float(raw.y << 16);
  v[3] = __uint_as_float(raw.y & 0xffff0000u);
  v[4] = __uint_as_float(raw.z << 16);
  v[5] = __uint_as_float(raw.z & 0xffff0000u);
  v[6] = __uint_as_float(raw.w << 16);
  v[7] = __uint_as_float(raw.w & 0xffff0000u);
}
__device__ __forceinline__ bf16x8 as_bf16x8(uint4 u) {
  union {
    uint4 u;
    bf16x8 b;
  } cv;
  cv.u = u;
  return cv.b;
}

// ---- coarse scatter + (appended blocks) f32->bf16 conversion of h0 ----
// conv also writes the layer-0 compact half tables cA0/cA1 (N x 32 bf16 each).
__global__ __launch_bounds__(256) void f2_coarse(
    const int* __restrict__ src, const int* __restrict__ dst,
    const int* __restrict__ et, int* __restrict__ gcur,
    unsigned* __restrict__ staging, int E, int nfb,
    const float* __restrict__ h0, ushort* __restrict__ hbA,
    ushort* __restrict__ cA0, ushort* __restrict__ cA1, int n4) {
  __shared__ int lcnt[256];
  __shared__ int sc[256];
  __shared__ int lbase[256];
  __shared__ int gb[256];
  __shared__ unsigned rec[EPB];
  __shared__ unsigned char rbk[EPB];

  const int t = threadIdx.x;

  if (blockIdx.x >= nfb) {  // ---- conv_bf16 part (h0 -> bf16 + compact) ----
    const int i = (blockIdx.x - nfb) * 256 + t;
    if (i < n4) {
      float4 v = ((const float4*)h0)[i];
      uint2 o;
      o.x = f2bf(v.x) | (f2bf(v.y) << 16);
      o.y = f2bf(v.z) | (f2bf(v.w) << 16);
      ((uint2*)hbA)[i] = o;
      const int n = i >> 4;
      const int c4 = (i & 15) << 2;           // col 0..60
      ushort* ch = (c4 < 32) ? cA0 : cA1;
      *(uint2*)(ch + n * 32 + (c4 & 31)) = o;
    }
    return;
  }

  const int base = blockIdx.x * EPB;
  const int rep = blockIdx.x & (NREP - 1);
  const int bc = min(EPB, E - base);

  lcnt[t] = 0;
  __syncthreads();

  int d_[EPB / 256], se_[EPB / 256], rk_[EPB / 256];
#pragma unroll
  for (int k = 0; k < EPB / 256; ++k) {
    const int e = base + k * 256 + t;
    if (e < E) {
      const int d = dst[e];
      d_[k] = d;
      se_[k] = (src[e] << 2) | et[e];
      rk_[k] = atomicAdd(&lcnt[d >> 8], 1);
    } else {
      d_[k] = -1;
    }
  }
  __syncthreads();

  const int lv = lcnt[t];
  sc[t] = lv;
  __syncthreads();
#pragma unroll
  for (int off = 1; off < 256; off <<= 1) {
    const int add = (t >= off) ? sc[t - off] : 0;
    __syncthreads();
    sc[t] += add;
    __syncthreads();
  }
  lbase[t] = sc[t] - lv;
  gb[t] = lv ? atomicAdd(&gcur[rep * 256 + t], lv) : 0;
  __syncthreads();

#pragma unroll
  for (int k = 0; k < EPB / 256; ++k) {
    if (d_[k] >= 0) {
      const int cb = d_[k] >> 8;
      const int pos = lbase[cb] + rk_[k];
      rec[pos] = ((unsigned)(d_[k] & 255) << 24) | (unsigned)se_[k];
      rbk[pos] = (unsigned char)cb;
    }
  }
  __syncthreads();

  for (int idx = t; idx < bc; idx += 256) {
    const int cb = rbk[idx];
    staging[gb[cb] + (idx - lbase[cb])] = rec[idx];
  }
}

// ---- fine placement, 4 sub-blocks per bucket, (dst,rel)-sorted output ----
// cscan2 folded; emits rowptr (per node, for gat) AND rowptr4 (per node,rel:
// segment starts for the branch-free gather).
// srcet record: (src << 8) | (dst_local6 << 2) | rel
__global__ __launch_bounds__(256) void f3_fine4(
    const unsigned* __restrict__ staging, const int* __restrict__ gcur,
    int* __restrict__ rowptr, int* __restrict__ rowptr4,
    int* __restrict__ srcet, int N, int CAP, int CAP8) {
  __shared__ int hist[256];
  __shared__ int sc[256];
  __shared__ int lcur[256];
  __shared__ int before;
  __shared__ int cb_base;
  const int cb = blockIdx.x >> 2;
  const int sub = blockIdx.x & 3;
  const int t = threadIdx.x;
  const int dlo = sub << 6;

  hist[t] = 0;
  if (t == 0) before = 0;

  // ---- local cbase scan ----
  int cc = 0;
#pragma unroll
  for (int r = 0; r < NREP; ++r)
    cc += gcur[r * 256 + t] - (t * CAP + r * CAP8);
  sc[t] = cc;
  __syncthreads();
#pragma unroll
  for (int off = 1; off < 256; off <<= 1) {
    const int add = (t >= off) ? sc[t - off] : 0;
    __syncthreads();
    sc[t] += add;
    __syncthreads();
  }
  if (t == cb) cb_base = sc[t] - cc;
  __syncthreads();

  int myb = 0;
#pragma unroll 1
  for (int r = 0; r < NREP; ++r) {
    const int s0 = cb * CAP + r * CAP8;
    const int s1 = gcur[r * 256 + cb];
    for (int i = s0 + t; i < s1; i += 256) {
      const unsigned rc = staging[i];
      const int dl = (int)(rc >> 24);
      const int off = dl - dlo;
      if ((unsigned)off < 64u)
        atomicAdd(&hist[(off << 2) | (int)(rc & 3u)], 1);
      else if (dl < dlo)
        ++myb;
    }
  }
#pragma unroll
  for (int off = 32; off > 0; off >>= 1) myb += __shfl_down(myb, off);
  if ((t & 63) == 0 && myb) atomicAdd(&before, myb);
  __syncthreads();

  const int v = hist[t];
  sc[t] = v;
  __syncthreads();
#pragma unroll
  for (int off = 1; off < 256; off <<= 1) {
    const int add = (t >= off) ? sc[t - off] : 0;
    __syncthreads();
    sc[t] += add;
    __syncthreads();
  }
  const int base = cb_base + before + sc[t] - v;
  lcur[t] = base;
  {
    const int dn = (cb << 8) + dlo + (t >> 2);
    if (dn < N) {
      rowptr4[(dn << 2) | (t & 3)] = base;  // segment start (node, rel)
      if ((t & 3) == 0) rowptr[dn] = base;
    }
  }
  __syncthreads();

#pragma unroll 1
  for (int r = 0; r < NREP; ++r) {
    const int s0 = cb * CAP + r * CAP8;
    const int s1 = gcur[r * 256 + cb];
    for (int i = s0 + t; i < s1; i += 256) {
      const unsigned rc = staging[i];
      const int dl = (int)(rc >> 24);
      const int off = dl - dlo;
      if ((unsigned)off < 64u) {
        const int pos = atomicAdd(&lcur[(off << 2) | (int)(rc & 3u)], 1);
        srcet[pos] =
            (int)((((rc & 0xFFFFFFu) >> 2) << 8) | ((unsigned)off << 2) |
                  (rc & 3u));
      }
    }
  }
}

// ====== gather v4: compact L2-resident half table + rel-segment loops ======
// Table hbC = N x 32 bf16 contiguous (3.2MB < 4MiB/XCD L2) -> random row reads
// become L2 hits after warmup (r5's strided halves shared 128B lines and never
// tested residency; FETCH=56MB showed 8x-XCD re-fetch of the full table).
// Edges are (dst,rel)-sorted; rowptr4 gives per-rel segments -> dedicated
// accumulator per segment, ZERO divergent rel-select VALU.
// Wave = 1 node; lane: g=slot(4 edges//), t=col-pair. srcet/aggr nontemporal.
__global__ __launch_bounds__(256) void gather_seg(
    const ushort* __restrict__ hbC, const int* __restrict__ rowptr4,
    const int* __restrict__ srcet, ushort* __restrict__ aggr_bf, int N,
    int half) {
  const int wv = threadIdx.x >> 6;
  const int lane = threadIdx.x & 63;
  const int g = lane >> 4;  // edge slot 0..3
  const int t = lane & 15;  // col pair {2t, 2t+1} within the 32-col half
  const int n = blockIdx.x * 4 + wv;
  if (n >= N) return;
  const int4 rp = *(const int4*)(rowptr4 + (n << 2));
  const int rpE = rowptr4[(n << 2) + 4];
  const unsigned* tb = (const unsigned*)hbC + t;  // row stride 16 uints

  float2 a0 = make_float2(0.f, 0.f);
  float2 a1 = a0, a2 = a0, a3 = a0;

#define SEG(B, E_, ACC)                                                      \
  {                                                                          \
    int j = (B) + g;                                                         \
    for (; j + 4 < (E_); j += 8) {                                           \
      const int s0 = __builtin_nontemporal_load(srcet + j) >> 8;             \
      const int s1 = __builtin_nontemporal_load(srcet + j + 4) >> 8;         \
      const unsigned w0 = tb[s0 << 4];                                       \
      const unsigned w1 = tb[s1 << 4];                                       \
      ACC.x += __uint_as_float(w0 << 16);                                    \
      ACC.y += __uint_as_float(w0 & 0xffff0000u);                            \
      ACC.x += __uint_as_float(w1 << 16);                                    \
      ACC.y += __uint_as_float(w1 & 0xffff0000u);                            \
    }                                                                        \
    if (j < (E_)) {                                                          \
      const int s0 = __builtin_nontemporal_load(srcet + j) >> 8;             \
      const unsigned w0 = tb[s0 << 4];                                       \
      ACC.x += __uint_as_float(w0 << 16);                                    \
      ACC.y += __uint_as_float(w0 & 0xffff0000u);                            \
    }                                                                        \
  }

  SEG(rp.x, rp.y, a0)
  SEG(rp.y, rp.z, a1)
  SEG(rp.z, rp.w, a2)
  SEG(rp.w, rpE, a3)
#undef SEG

#pragma unroll
  for (int off = 16; off <= 32; off <<= 1) {
    a0.x += __shfl_xor(a0.x, off); a0.y += __shfl_xor(a0.y, off);
    a1.x += __shfl_xor(a1.x, off); a1.y += __shfl_xor(a1.y, off);
    a2.x += __shfl_xor(a2.x, off); a2.y += __shfl_xor(a2.y, off);
    a3.x += __shfl_xor(a3.x, off); a3.y += __shfl_xor(a3.y, off);
  }

  const float2 res = (g == 0) ? a0 : (g == 1) ? a1 : (g == 2) ? a2 : a3;
  const unsigned p = f2bf(res.x) | (f2bf(res.y) << 16);
  unsigned* dstp =
      (unsigned*)(aggr_bf + ((size_t)n << 8) + (g << 6) + (half << 5) +
                  (t << 1));
  __builtin_nontemporal_store(p, dstp);
}

// ====== pack RGCN weights (MFMA B-frag bf16) + GAT vectors + init block ======
__global__ __launch_bounds__(256) void pack_w(
    const float* __restrict__ Wrel, const float* __restrict__ Wloop,
    const float* __restrict__ Wg, const float* __restrict__ al,
    const float* __restrict__ ar, const float* __restrict__ Wd,
    ushort* __restrict__ wpk, float* __restrict__ vav, int L,
    float* __restrict__ out, const float* __restrict__ bd, int out_n,
    unsigned* __restrict__ genc, int* __restrict__ gcur, int CAP, int CAP8,
    int* __restrict__ rowptr, int* __restrict__ rowptr4, int N, int E) {
  const int l = blockIdx.x;
  if (l < L) {
    for (int f = threadIdx.x; f < 2560; f += 256) {
      const int lane = f & 63;
      const int kc = f >> 6;  // kt*4 + c
      const int kt = kc >> 2;
      const int c = kc & 3;
      const int o = c * 16 + (lane & 15);
      const int kl0 = (lane >> 4) * 8;
      const float* wsrc =
          (kt < 8)
              ? Wrel + ((((size_t)l * 4 + (kt >> 1)) * 64 + (kt & 1) * 32 + kl0) * 64)
              : Wloop + (((size_t)l * 64 + (kt - 8) * 32 + kl0) * 64);
      unsigned o8[8];
#pragma unroll
      for (int j = 0; j < 8; ++j) o8[j] = f2bf(wsrc[(size_t)j * 64 + o]);
      uint4 p;
      p.x = o8[0] | (o8[1] << 16);
      p.y = o8[2] | (o8[3] << 16);
      p.z = o8[4] | (o8[5] << 16);
      p.w = o8[6] | (o8[7] << 16);
      *(uint4*)(wpk + (size_t)l * 20480 + (size_t)f * 8) = p;
    }
  } else if (l == L) {
    // va = Wg@al, vr = Wg@ar, vd = Wg@Wd
    const int tt = threadIdx.x;
    if (tt < 192) {
      const int which = tt >> 6;
      const int d = tt & 63;
      const float* v = (which == 0) ? al : (which == 1) ? ar : Wd;
      float s = 0.f;
#pragma unroll
      for (int o = 0; o < 64; ++o) s = fmaf(Wg[d * 64 + o], v[o], s);
      vav[tt] = s;
    }
  } else {
    // init: out = bd, gcur bases, genc = -inf, rowptr[N] = rowptr4[4N] = E
    const int tt = threadIdx.x;
    for (int i = tt; i < out_n; i += 256) out[i] = bd[0];
    for (int i = tt; i < 256 * NREP; i += 256) {
      const int r = i >> 8;
      const int b = i & 255;
      gcur[i] = b * CAP + r * CAP8;
    }
    if (tt == 0) {
      *genc = enc_f32(-1e30f);
      rowptr[N] = E;
      rowptr4[N << 2] = E;
    }
  }
}

// == dense via MFMA: hb_out = bf16(relu([aggr|h] @ [Wrel;Wloop] + b)) ==
// Epilogue also writes the NEXT layer's compact half tables c0/c1.
__global__ __launch_bounds__(256) void rgcn_dense_mfma(
    const ushort* __restrict__ aggr_bf, const ushort* __restrict__ hb_in,
    const ushort* __restrict__ wpk, const float* __restrict__ bias,
    ushort* __restrict__ hb_out, ushort* __restrict__ c0,
    ushort* __restrict__ c1, int N) {
  __shared__ __align__(16) char smraw[40960];  // B frags; reused as f32 out-tile
  const int tid = threadIdx.x;

  {  // stage packed W (320x64 bf16 = 2560 uint4) into LDS
    const uint4* gsrc = (const uint4*)wpk;
    uint4* ldst = (uint4*)smraw;
#pragma unroll
    for (int i = 0; i < 10; ++i) ldst[i * 256 + tid] = gsrc[i * 256 + tid];
  }

  const int w = tid >> 6;
  const int lane = tid & 63;
  const int t = lane & 15;
  const int g = lane >> 4;
  const int n = blockIdx.x * 64 + w * 16 + t;
  const bool valid = n < N;

  f32x4 acc[4];
#pragma unroll
  for (int c = 0; c < 4; ++c) {
    const float b = bias[c * 16 + t];
    f32x4 z = {b, b, b, b};
    acc[c] = z;
  }

  __syncthreads();
  const bf16x8* bfr = (const bf16x8*)smraw;

#pragma unroll
  for (int kt = 0; kt < 10; ++kt) {
    uint4 raw = make_uint4(0u, 0u, 0u, 0u);
    if (valid) {
      const ushort* ap =
          (kt < 8) ? aggr_bf + (((size_t)n) << 8) + (kt << 5) + (g << 3)
                   : hb_in + (((size_t)n) << 6) + ((kt - 8) << 5) + (g << 3);
      raw = *(const uint4*)ap;
    }
    const bf16x8 a = as_bf16x8(raw);
#pragma unroll
    for (int c = 0; c < 4; ++c) {
      acc[c] = __builtin_amdgcn_mfma_f32_16x16x32_bf16(
          a, bfr[(kt * 4 + c) * 64 + lane], acc[c], 0, 0, 0);
    }
  }

  __syncthreads();  // all waves done reading B frags
  float* tile = (float*)smraw;
  {
    // D layout: col = lane&15, row = (lane>>4)*4 + reg  [m89/m91]
    const int r0 = w * 16 + g * 4;
#pragma unroll
    for (int c = 0; c < 4; ++c) {
      const int col = c * 16 + t;
#pragma unroll
      for (int r = 0; r < 4; ++r)
        tile[(r0 + r) * 65 + col] = fmaxf(acc[c][r], 0.f);
    }
  }
  __syncthreads();
  const int n0 = blockIdx.x * 64;
#pragma unroll
  for (int q = 0; q < 2; ++q) {
    const int f = q * 256 + tid;
    const int row = f >> 3;
    const int c8 = (f & 7) << 3;
    const int nn = n0 + row;
    if (nn < N) {
      const float* s = tile + row * 65 + c8;
      uint4 p;
      p.x = f2bf(s[0]) | (f2bf(s[1]) << 16);
      p.y = f2bf(s[2]) | (f2bf(s[3]) << 16);
      p.z = f2bf(s[4]) | (f2bf(s[5]) << 16);
      p.w = f2bf(s[6]) | (f2bf(s[7]) << 16);
      *(uint4*)(hb_out + (((size_t)nn) << 6) + c8) = p;
      ushort* ch = (c8 < 32) ? c0 : c1;
      *(uint4*)(ch + (size_t)nn * 32 + (c8 & 31)) = p;
    }
  }
}

// ===== GAT projection via fused vectors: ely={h.va,h.vd}, er=h.vr =====
__global__ __launch_bounds__(256) void gat_proj(
    const ushort* __restrict__ hb, const float* __restrict__ vav,
    float2* __restrict__ ely, float* __restrict__ er,
    unsigned* __restrict__ genc, int N) {
  __shared__ float sv[192];
  const int tid = threadIdx.x;
  if (tid < 192) sv[tid] = vav[tid];
  __syncthreads();
  const int n = blockIdx.x * 256 + tid;
  float pl = 0.f, pr = 0.f, py = 0.f;
  if (n < N) {
    const ushort* row = hb + ((size_t)n << 6);
#pragma unroll
    for (int q = 0; q < 8; ++q) {
      const uint4 raw = *(const uint4*)(row + (q << 3));
      float v[8];
      unpack8(raw, v);
#pragma unroll
      for (int j = 0; j < 8; ++j) {
        pl = fmaf(v[j], sv[q * 8 + j], pl);
        pr = fmaf(v[j], sv[64 + q * 8 + j], pr);
        py = fmaf(v[j], sv[128 + q * 8 + j], py);
      }
    }
    ely[n] = make_float2(pl, py);
    er[n] = pr;
  }
  float mx = (n < N) ? pl : -1e30f;
#pragma unroll
  for (int off = 32; off > 0; off >>= 1) mx = fmaxf(mx, __shfl_xor(mx, off));
  if ((tid & 63) == 0) atomicMax(genc, enc_f32(mx));
}

// ===== scalar GAT aggregation + pooling, 16 lanes/node =====
#define GSC_NPG 2
#define GSC_NPB (16 * GSC_NPG)
__global__ __launch_bounds__(256) void gat_scalar(
    const float2* __restrict__ ely, const float* __restrict__ er,
    const int* __restrict__ rowptr, const int* __restrict__ srcet,
    const unsigned* __restrict__ genc, const int* __restrict__ gids,
    float* __restrict__ out, int N, int B) {
  __shared__ float acc[256];
  for (int i = threadIdx.x; i < B; i += 256) acc[i] = 0.f;
  __syncthreads();
  const int grp = threadIdx.x >> 4;
  const int ln = threadIdx.x & 15;
  const float gmax = dec_f32(*genc);
  const int base = blockIdx.x * GSC_NPB + grp * GSC_NPG;

#pragma unroll
  for (int i = 0; i < GSC_NPG; ++i) {
    const int n = base + i;
    if (n < N) {
      const int beg = rowptr[n], end = rowptr[n + 1];
      const float ern = er[n];
      float mb = gmax + ern;
      mb = (mb > 0.f) ? mb : 0.2f * mb;
      float num = 0.f, den = 0.f;
      for (int j = beg + ln; j < end; j += 16) {
        const float2 e2 = ely[srcet[j] >> 8];  // {el, y} one 8B gather
        float x = e2.x + ern;
        x = (x > 0.f) ? x : 0.2f * x;
        const float w = __expf(x - mb);
        num = fmaf(w, e2.y, num);
        den += w;
      }
#pragma unroll
      for (int off = 1; off < 16; off <<= 1) {
        num += __shfl_xor(num, off);
        den += __shfl_xor(den, off);
      }
      if (ln == 0) atomicAdd(&acc[gids[n]], num / fmaxf(den, 1e-9f));
    }
  }
  __syncthreads();
  for (int i = threadIdx.x; i < B; i += 256) {
    const float v = acc[i];
    if (v != 0.f) unsafeAtomicAdd(out + i, v);
  }
}

// ================= launch =================
extern "C" void kernel_launch(void* const* d_in, const int* in_sizes, int n_in,
                              void* d_out, int out_size, void* d_ws,
                              size_t ws_size, hipStream_t stream) {
  const float* h0 = (const float*)d_in[0];
  const float* Wrel = (const float*)d_in[1];
  const float* Wloop = (const float*)d_in[2];
  const float* brel = (const float*)d_in[3];
  const float* Wg = (const float*)d_in[4];
  const float* al = (const float*)d_in[5];
  const float* ar = (const float*)d_in[6];
  const float* Wd = (const float*)d_in[7];
  const float* bd = (const float*)d_in[8];
  const int* src = (const int*)d_in[9];
  const int* dst = (const int*)d_in[10];
  const int* et = (const int*)d_in[11];
  const int* gids = (const int*)d_in[12];

  const int N = in_sizes[0] / DD;
  const int E = in_sizes[9];
  const int L = in_sizes[2] / (DD * DD);
  float* out = (float*)d_out;
  const int CAP8 = ((E / (256 * NREP)) * 2 + 63) & ~63;
  const int CAP = CAP8 * NREP;

  // ---- workspace layout ----
  char* wsb = (char*)d_ws;
  ushort* hbA = (ushort*)wsb;                    // N*64 bf16
  ushort* hbB = hbA + (size_t)N * DD;            // N*64 bf16
  ushort* cA0 = hbB + (size_t)N * DD;            // N*32 bf16 compact tables
  ushort* cA1 = cA0 + (size_t)N * 32;
  ushort* cB0 = cA1 + (size_t)N * 32;
  ushort* cB1 = cB0 + (size_t)N * 32;
  ushort* aggr_bf = cB1 + (size_t)N * 32;        // N*256 bf16 (25.6MB region)
  int* rowptr = (int*)(aggr_bf + (size_t)N * 256);  // N+1
  int* srcet = rowptr + N + 1;                   // E
  int* rowptr4 = (int*)(((size_t)(srcet + E) + 15) & ~(size_t)15);  // 4N+8
  float2* ely = (float2*)(rowptr4 + 4 * N + 8);  // N float2 {el,y}
  float* er = (float*)(ely + N);                 // N
  int* gcur = (int*)(er + N);                    // 256*NREP
  unsigned* genc = (unsigned*)(gcur + 256 * NREP);  // 1
  unsigned* staging = (unsigned*)aggr_bf;        // 256*CAP uints
  float* vav = (float*)(genc + 1);               // 192 floats (va|vr|vd)
  // packed W (L*20480 bf16 = 160KB) overlaps ely (dead until gat_proj).
  ushort* wpk = (ushort*)(((size_t)(char*)ely + 15) & ~(size_t)15);

  dim3 b256(256);
  const int grid_dense = (N + 63) / 64;
  const int nfb = (E + EPB - 1) / EPB;
  const int ncb = (N + 255) >> 8;
  const int n4 = N * DD / 4;
  const int ncv = (n4 + 255) / 256;

  // ---- weight packing + GAT vectors + init (block L+1) ----
  hipLaunchKernelGGL(pack_w, dim3(L + 2), b256, 0, stream, Wrel, Wloop, Wg, al,
                     ar, Wd, wpk, vav, L, out, bd, out_size, genc, gcur, CAP,
                     CAP8, rowptr, rowptr4, N, E);

  // ---- CSR build (+ appended conv blocks: h0 -> bf16 + compact tables) ----
  hipLaunchKernelGGL(f2_coarse, dim3(nfb + ncv), b256, 0, stream, src, dst, et,
                     gcur, staging, E, nfb, h0, hbA, cA0, cA1, n4);
  hipLaunchKernelGGL(f3_fine4, dim3(ncb * 4), b256, 0, stream, staging, gcur,
                     rowptr, rowptr4, srcet, N, CAP, CAP8);

  // ---- RGCN layers (2x compact-table segment gather + MFMA dense) ----
  ushort* cur = hbA;
  ushort* nxt = hbB;
  ushort* c0 = cA0;
  ushort* c1 = cA1;
  ushort* d0 = cB0;
  ushort* d1 = cB1;
  const int grid_g = (N + 3) / 4;
  for (int l = 0; l < L; ++l) {
    hipLaunchKernelGGL(gather_seg, dim3(grid_g), b256, 0, stream, c0, rowptr4,
                       srcet, aggr_bf, N, 0);
    hipLaunchKernelGGL(gather_seg, dim3(grid_g), b256, 0, stream, c1, rowptr4,
                       srcet, aggr_bf, N, 1);
    hipLaunchKernelGGL(rgcn_dense_mfma, dim3(grid_dense), b256, 0, stream,
                       aggr_bf, cur, wpk + (size_t)l * 20480,
                       brel + (size_t)l * DD, nxt, d0, d1, N);
    ushort* tmp = cur; cur = nxt; nxt = tmp;
    ushort* t0 = c0; c0 = d0; d0 = t0;
    ushort* t1 = c1; c1 = d1; d1 = t1;
  }

  // ---- GAT: fused projection, then scalar aggregation + pooling ----
  hipLaunchKernelGGL(gat_proj, dim3((N + 255) / 256), b256, 0, stream, cur, vav,
                     ely, er, genc, N);
  const int grid_gs = (N + GSC_NPB - 1) / GSC_NPB;
  hipLaunchKernelGGL(gat_scalar, dim3(grid_gs), b256, 0, stream, ely, er,
                     rowptr, srcet, genc, gids, out, N, out_size);
}

// Round 10
// 353.275 us; speedup vs baseline: 1.6626x; 1.6626x over previous
//
#include <hip/hip_runtime.h>

#define DD 64
#define EPB 1024  // edges per block in fill pipeline
#define NREP 8    // gcur replicas (anti-serialization)

typedef float f32x4 __attribute__((ext_vector_type(4)));
typedef __bf16 bf16x8 __attribute__((ext_vector_type(8)));

__device__ __forceinline__ unsigned enc_f32(float x) {
  unsigned u = __float_as_uint(x);
  return (u & 0x80000000u) ? ~u : (u | 0x80000000u);
}
__device__ __forceinline__ float dec_f32(unsigned k) {
  return (k & 0x80000000u) ? __uint_as_float(k ^ 0x80000000u)
                           : __uint_as_float(~k);
}
__device__ __forceinline__ unsigned f2bf(float x) {
  unsigned u = __float_as_uint(x);
  return (u + 0x7fffu + ((u >> 16) & 1u)) >> 16;
}
__device__ __forceinline__ void unpack8(const uint4 raw, float* v) {
  v[0] = __uint_as_float(raw.x << 16);
  v[1] = __uint_as_float(raw.x & 0xffff0000u);
  v[2] = __uint_as_float(raw.y << 16);
  v[3] = __uint_as_float(raw.y & 0xffff0000u);
  v[4] = __uint_as_float(raw.z << 16);
  v[5] = __uint_as_float(raw.z & 0xffff0000u);
  v[6] = __uint_as_float(raw.w << 16);
  v[7] = __uint_as_float(raw.w & 0xffff0000u);
}
__device__ __forceinline__ float4 unpack4(const uint2 r) {
  return make_float4(__uint_as_float(r.x << 16),
                     __uint_as_float(r.x & 0xffff0000u),
                     __uint_as_float(r.y << 16),
                     __uint_as_float(r.y & 0xffff0000u));
}
__device__ __forceinline__ bf16x8 as_bf16x8(uint4 u) {
  union {
    uint4 u;
    bf16x8 b;
  } cv;
  cv.u = u;
  return cv.b;
}

// ---- coarse scatter + (appended blocks) f32->bf16 conversion of h0 ----
__global__ __launch_bounds__(256) void f2_coarse(
    const int* __restrict__ src, const int* __restrict__ dst,
    const int* __restrict__ et, int* __restrict__ gcur,
    unsigned* __restrict__ staging, int E, int nfb,
    const float* __restrict__ h0, ushort* __restrict__ hbA, int n4) {
  __shared__ int lcnt[256];
  __shared__ int sc[256];
  __shared__ int lbase[256];
  __shared__ int gb[256];
  __shared__ unsigned rec[EPB];
  __shared__ unsigned char rbk[EPB];

  const int t = threadIdx.x;

  if (blockIdx.x >= nfb) {  // ---- conv_bf16 part (h0 -> bf16) ----
    const int i = (blockIdx.x - nfb) * 256 + t;
    if (i < n4) {
      float4 v = ((const float4*)h0)[i];
      uint2 o;
      o.x = f2bf(v.x) | (f2bf(v.y) << 16);
      o.y = f2bf(v.z) | (f2bf(v.w) << 16);
      ((uint2*)hbA)[i] = o;
    }
    return;
  }

  const int base = blockIdx.x * EPB;
  const int rep = blockIdx.x & (NREP - 1);
  const int bc = min(EPB, E - base);

  lcnt[t] = 0;
  __syncthreads();

  int d_[EPB / 256], se_[EPB / 256], rk_[EPB / 256];
#pragma unroll
  for (int k = 0; k < EPB / 256; ++k) {
    const int e = base + k * 256 + t;
    if (e < E) {
      const int d = dst[e];
      d_[k] = d;
      se_[k] = (src[e] << 2) | et[e];
      rk_[k] = atomicAdd(&lcnt[d >> 8], 1);
    } else {
      d_[k] = -1;
    }
  }
  __syncthreads();

  const int lv = lcnt[t];
  sc[t] = lv;
  __syncthreads();
#pragma unroll
  for (int off = 1; off < 256; off <<= 1) {
    const int add = (t >= off) ? sc[t - off] : 0;
    __syncthreads();
    sc[t] += add;
    __syncthreads();
  }
  lbase[t] = sc[t] - lv;
  gb[t] = lv ? atomicAdd(&gcur[rep * 256 + t], lv) : 0;
  __syncthreads();

#pragma unroll
  for (int k = 0; k < EPB / 256; ++k) {
    if (d_[k] >= 0) {
      const int cb = d_[k] >> 8;
      const int pos = lbase[cb] + rk_[k];
      rec[pos] = ((unsigned)(d_[k] & 255) << 24) | (unsigned)se_[k];
      rbk[pos] = (unsigned char)cb;
    }
  }
  __syncthreads();

  for (int idx = t; idx < bc; idx += 256) {
    const int cb = rbk[idx];
    staging[gb[cb] + (idx - lbase[cb])] = rec[idx];
  }
}

// ---- fine placement, 4 sub-blocks per bucket, (dst,rel)-sorted output ----
// cscan2 folded in: each block recomputes the 256-bucket exclusive prefix.
// srcet record: (src << 8) | (dst_local6 << 2) | rel   (src < 2^16: N = 50K)
__global__ __launch_bounds__(256) void f3_fine4(
    const unsigned* __restrict__ staging, const int* __restrict__ gcur,
    int* __restrict__ rowptr, int* __restrict__ srcet, int N, int CAP,
    int CAP8) {
  __shared__ int hist[256];
  __shared__ int sc[256];
  __shared__ int lcur[256];
  __shared__ int before;
  __shared__ int cb_base;
  const int cb = blockIdx.x >> 2;
  const int sub = blockIdx.x & 3;
  const int t = threadIdx.x;
  const int dlo = sub << 6;

  hist[t] = 0;
  if (t == 0) before = 0;

  // ---- local cbase scan (replaces cscan2 dispatch) ----
  int cc = 0;
#pragma unroll
  for (int r = 0; r < NREP; ++r)
    cc += gcur[r * 256 + t] - (t * CAP + r * CAP8);
  sc[t] = cc;
  __syncthreads();
#pragma unroll
  for (int off = 1; off < 256; off <<= 1) {
    const int add = (t >= off) ? sc[t - off] : 0;
    __syncthreads();
    sc[t] += add;
    __syncthreads();
  }
  if (t == cb) cb_base = sc[t] - cc;  // exclusive prefix at bucket cb
  __syncthreads();

  int myb = 0;
#pragma unroll 1
  for (int r = 0; r < NREP; ++r) {
    const int s0 = cb * CAP + r * CAP8;
    const int s1 = gcur[r * 256 + cb];
    for (int i = s0 + t; i < s1; i += 256) {
      const unsigned rc = staging[i];
      const int dl = (int)(rc >> 24);
      const int off = dl - dlo;
      if ((unsigned)off < 64u)
        atomicAdd(&hist[(off << 2) | (int)(rc & 3u)], 1);
      else if (dl < dlo)
        ++myb;
    }
  }
#pragma unroll
  for (int off = 32; off > 0; off >>= 1) myb += __shfl_down(myb, off);
  if ((t & 63) == 0 && myb) atomicAdd(&before, myb);
  __syncthreads();

  const int v = hist[t];
  sc[t] = v;
  __syncthreads();
#pragma unroll
  for (int off = 1; off < 256; off <<= 1) {
    const int add = (t >= off) ? sc[t - off] : 0;
    __syncthreads();
    sc[t] += add;
    __syncthreads();
  }
  const int base = cb_base + before + sc[t] - v;
  lcur[t] = base;
  if ((t & 3) == 0) {
    const int dn = (cb << 8) + dlo + (t >> 2);
    if (dn < N) rowptr[dn] = base;
  }
  __syncthreads();

#pragma unroll 1
  for (int r = 0; r < NREP; ++r) {
    const int s0 = cb * CAP + r * CAP8;
    const int s1 = gcur[r * 256 + cb];
    for (int i = s0 + t; i < s1; i += 256) {
      const unsigned rc = staging[i];
      const int dl = (int)(rc >> 24);
      const int off = dl - dlo;
      if ((unsigned)off < 64u) {
        const int pos = atomicAdd(&lcur[(off << 2) | (int)(rc & 3u)], 1);
        srcet[pos] =
            (int)((((rc & 0xFFFFFFu) >> 2) << 8) | ((unsigned)off << 2) |
                  (rc & 3u));
      }
    }
  }
}

// ====== per-node relation gather (PROVEN r3 structure, se>>8 encoding) ======
// 16 lanes/edge, uint2 loads (full 128B row = exactly 1 line-request/edge =
// the algorithmic minimum per the r3..r9 line-request law), 8 edges in
// flight, monolithic loop. 45 µs/dispatch measured floor.
#define ACCUM(se, v)                                                         \
  {                                                                          \
    const int r_ = (se) & 3;                                                 \
    if (r_ == 0) { a0.x += v.x; a0.y += v.y; a0.z += v.z; a0.w += v.w; }     \
    else if (r_ == 1) { a1.x += v.x; a1.y += v.y; a1.z += v.z; a1.w += v.w; }\
    else if (r_ == 2) { a2.x += v.x; a2.y += v.y; a2.z += v.z; a2.w += v.w; }\
    else { a3.x += v.x; a3.y += v.y; a3.z += v.z; a3.w += v.w; }             \
  }

__global__ __launch_bounds__(256) void gather_rel(
    const ushort* __restrict__ hb, const int* __restrict__ rowptr,
    const int* __restrict__ srcet, ushort* __restrict__ aggr_bf, int N) {
  const int n = blockIdx.x * 4 + (threadIdx.x >> 6);
  const int lane = threadIdx.x & 63;
  const int g = lane >> 4;    // edge slot 0..3
  const int t = lane & 15;    // elements [4t, 4t+4)
  if (n >= N) return;
  const int beg = rowptr[n], end = rowptr[n + 1];
  const ushort* hbt = hb + (t << 2);

  float4 a0 = make_float4(0.f, 0.f, 0.f, 0.f);
  float4 a1 = a0, a2 = a0, a3 = a0;

  int j = beg + g;
  for (; j + 28 < end; j += 32) {  // 8 edges in flight per lane
    const int se0 = srcet[j];
    const int se1 = srcet[j + 4];
    const int se2 = srcet[j + 8];
    const int se3 = srcet[j + 12];
    const int se4 = srcet[j + 16];
    const int se5 = srcet[j + 20];
    const int se6 = srcet[j + 24];
    const int se7 = srcet[j + 28];
    const uint2 r0 = *(const uint2*)(hbt + ((size_t)(se0 >> 8) << 6));
    const uint2 r1 = *(const uint2*)(hbt + ((size_t)(se1 >> 8) << 6));
    const uint2 r2 = *(const uint2*)(hbt + ((size_t)(se2 >> 8) << 6));
    const uint2 r3 = *(const uint2*)(hbt + ((size_t)(se3 >> 8) << 6));
    const uint2 r4 = *(const uint2*)(hbt + ((size_t)(se4 >> 8) << 6));
    const uint2 r5 = *(const uint2*)(hbt + ((size_t)(se5 >> 8) << 6));
    const uint2 r6 = *(const uint2*)(hbt + ((size_t)(se6 >> 8) << 6));
    const uint2 r7 = *(const uint2*)(hbt + ((size_t)(se7 >> 8) << 6));
    const float4 v0 = unpack4(r0);
    const float4 v1 = unpack4(r1);
    const float4 v2 = unpack4(r2);
    const float4 v3 = unpack4(r3);
    const float4 v4 = unpack4(r4);
    const float4 v5 = unpack4(r5);
    const float4 v6 = unpack4(r6);
    const float4 v7 = unpack4(r7);
    ACCUM(se0, v0);
    ACCUM(se1, v1);
    ACCUM(se2, v2);
    ACCUM(se3, v3);
    ACCUM(se4, v4);
    ACCUM(se5, v5);
    ACCUM(se6, v6);
    ACCUM(se7, v7);
  }
  for (; j + 12 < end; j += 16) {  // 4 in flight
    const int se0 = srcet[j];
    const int se1 = srcet[j + 4];
    const int se2 = srcet[j + 8];
    const int se3 = srcet[j + 12];
    const uint2 r0 = *(const uint2*)(hbt + ((size_t)(se0 >> 8) << 6));
    const uint2 r1 = *(const uint2*)(hbt + ((size_t)(se1 >> 8) << 6));
    const uint2 r2 = *(const uint2*)(hbt + ((size_t)(se2 >> 8) << 6));
    const uint2 r3 = *(const uint2*)(hbt + ((size_t)(se3 >> 8) << 6));
    const float4 v0 = unpack4(r0);
    const float4 v1 = unpack4(r1);
    const float4 v2 = unpack4(r2);
    const float4 v3 = unpack4(r3);
    ACCUM(se0, v0);
    ACCUM(se1, v1);
    ACCUM(se2, v2);
    ACCUM(se3, v3);
  }
  for (; j < end; j += 4) {
    const int se0 = srcet[j];
    const uint2 r0 = *(const uint2*)(hbt + ((size_t)(se0 >> 8) << 6));
    const float4 v0 = unpack4(r0);
    ACCUM(se0, v0);
  }

#pragma unroll
  for (int off = 16; off <= 32; off <<= 1) {
    a0.x += __shfl_xor(a0.x, off); a0.y += __shfl_xor(a0.y, off);
    a0.z += __shfl_xor(a0.z, off); a0.w += __shfl_xor(a0.w, off);
    a1.x += __shfl_xor(a1.x, off); a1.y += __shfl_xor(a1.y, off);
    a1.z += __shfl_xor(a1.z, off); a1.w += __shfl_xor(a1.w, off);
    a2.x += __shfl_xor(a2.x, off); a2.y += __shfl_xor(a2.y, off);
    a2.z += __shfl_xor(a2.z, off); a2.w += __shfl_xor(a2.w, off);
    a3.x += __shfl_xor(a3.x, off); a3.y += __shfl_xor(a3.y, off);
    a3.z += __shfl_xor(a3.z, off); a3.w += __shfl_xor(a3.w, off);
  }

  const float4 res = (g == 0) ? a0 : (g == 1) ? a1 : (g == 2) ? a2 : a3;
  uint2 p;
  p.x = f2bf(res.x) | (f2bf(res.y) << 16);
  p.y = f2bf(res.z) | (f2bf(res.w) << 16);
  *(uint2*)(aggr_bf + ((size_t)n << 8) + (g << 6) + (t << 2)) = p;
}

// ====== pack RGCN weights (MFMA B-frag bf16) + GAT vectors + init block ======
__global__ __launch_bounds__(256) void pack_w(
    const float* __restrict__ Wrel, const float* __restrict__ Wloop,
    const float* __restrict__ Wg, const float* __restrict__ al,
    const float* __restrict__ ar, const float* __restrict__ Wd,
    ushort* __restrict__ wpk, float* __restrict__ vav, int L,
    float* __restrict__ out, const float* __restrict__ bd, int out_n,
    unsigned* __restrict__ genc, int* __restrict__ gcur, int CAP, int CAP8,
    int* __restrict__ rowptr, int N, int E) {
  const int l = blockIdx.x;
  if (l < L) {
    for (int f = threadIdx.x; f < 2560; f += 256) {
      const int lane = f & 63;
      const int kc = f >> 6;  // kt*4 + c
      const int kt = kc >> 2;
      const int c = kc & 3;
      const int o = c * 16 + (lane & 15);
      const int kl0 = (lane >> 4) * 8;
      const float* wsrc =
          (kt < 8)
              ? Wrel + ((((size_t)l * 4 + (kt >> 1)) * 64 + (kt & 1) * 32 + kl0) * 64)
              : Wloop + (((size_t)l * 64 + (kt - 8) * 32 + kl0) * 64);
      unsigned o8[8];
#pragma unroll
      for (int j = 0; j < 8; ++j) o8[j] = f2bf(wsrc[(size_t)j * 64 + o]);
      uint4 p;
      p.x = o8[0] | (o8[1] << 16);
      p.y = o8[2] | (o8[3] << 16);
      p.z = o8[4] | (o8[5] << 16);
      p.w = o8[6] | (o8[7] << 16);
      *(uint4*)(wpk + (size_t)l * 20480 + (size_t)f * 8) = p;
    }
  } else if (l == L) {
    // va = Wg@al, vr = Wg@ar, vd = Wg@Wd  (z never materialized downstream)
    const int tt = threadIdx.x;
    if (tt < 192) {
      const int which = tt >> 6;
      const int d = tt & 63;
      const float* v = (which == 0) ? al : (which == 1) ? ar : Wd;
      float s = 0.f;
#pragma unroll
      for (int o = 0; o < 64; ++o) s = fmaf(Wg[d * 64 + o], v[o], s);
      vav[tt] = s;
    }
  } else {
    // init block: out = bd, gcur sub-slice bases, genc = -inf, rowptr[N] = E
    const int tt = threadIdx.x;
    for (int i = tt; i < out_n; i += 256) out[i] = bd[0];
    for (int i = tt; i < 256 * NREP; i += 256) {
      const int r = i >> 8;
      const int b = i & 255;
      gcur[i] = b * CAP + r * CAP8;
    }
    if (tt == 0) {
      *genc = enc_f32(-1e30f);
      rowptr[N] = E;
    }
  }
}

// == dense via MFMA: hb_out = bf16(relu([aggr|h] @ [Wrel;Wloop] + b)) ==
__global__ __launch_bounds__(256) void rgcn_dense_mfma(
    const ushort* __restrict__ aggr_bf, const ushort* __restrict__ hb_in,
    const ushort* __restrict__ wpk, const float* __restrict__ bias,
    ushort* __restrict__ hb_out, int N) {
  __shared__ __align__(16) char smraw[40960];  // B frags; reused as f32 out-tile
  const int tid = threadIdx.x;

  {  // stage packed W (320x64 bf16 = 2560 uint4) into LDS
    const uint4* gsrc = (const uint4*)wpk;
    uint4* ldst = (uint4*)smraw;
#pragma unroll
    for (int i = 0; i < 10; ++i) ldst[i * 256 + tid] = gsrc[i * 256 + tid];
  }

  const int w = tid >> 6;
  const int lane = tid & 63;
  const int t = lane & 15;
  const int g = lane >> 4;
  const int n = blockIdx.x * 64 + w * 16 + t;
  const bool valid = n < N;

  f32x4 acc[4];
#pragma unroll
  for (int c = 0; c < 4; ++c) {
    const float b = bias[c * 16 + t];
    f32x4 z = {b, b, b, b};
    acc[c] = z;
  }

  __syncthreads();
  const bf16x8* bfr = (const bf16x8*)smraw;

#pragma unroll
  for (int kt = 0; kt < 10; ++kt) {
    uint4 raw = make_uint4(0u, 0u, 0u, 0u);
    if (valid) {
      const ushort* ap =
          (kt < 8) ? aggr_bf + (((size_t)n) << 8) + (kt << 5) + (g << 3)
                   : hb_in + (((size_t)n) << 6) + ((kt - 8) << 5) + (g << 3);
      raw = *(const uint4*)ap;
    }
    const bf16x8 a = as_bf16x8(raw);
#pragma unroll
    for (int c = 0; c < 4; ++c) {
      acc[c] = __builtin_amdgcn_mfma_f32_16x16x32_bf16(
          a, bfr[(kt * 4 + c) * 64 + lane], acc[c], 0, 0, 0);
    }
  }

  __syncthreads();  // all waves done reading B frags
  float* tile = (float*)smraw;
  {
    // D layout: col = lane&15, row = (lane>>4)*4 + reg  [m89/m91]
    const int r0 = w * 16 + g * 4;
#pragma unroll
    for (int c = 0; c < 4; ++c) {
      const int col = c * 16 + t;
#pragma unroll
      for (int r = 0; r < 4; ++r)
        tile[(r0 + r) * 65 + col] = fmaxf(acc[c][r], 0.f);
    }
  }
  __syncthreads();
  const int n0 = blockIdx.x * 64;
#pragma unroll
  for (int q = 0; q < 2; ++q) {
    const int f = q * 256 + tid;
    const int row = f >> 3;
    const int c8 = (f & 7) << 3;
    const int nn = n0 + row;
    if (nn < N) {
      const float* s = tile + row * 65 + c8;
      uint4 p;
      p.x = f2bf(s[0]) | (f2bf(s[1]) << 16);
      p.y = f2bf(s[2]) | (f2bf(s[3]) << 16);
      p.z = f2bf(s[4]) | (f2bf(s[5]) << 16);
      p.w = f2bf(s[6]) | (f2bf(s[7]) << 16);
      *(uint4*)(hb_out + (((size_t)nn) << 6) + c8) = p;
    }
  }
}

// ===== GAT projection via fused vectors: ely={h.va,h.vd}, er=h.vr =====
__global__ __launch_bounds__(256) void gat_proj(
    const ushort* __restrict__ hb, const float* __restrict__ vav,
    float2* __restrict__ ely, float* __restrict__ er,
    unsigned* __restrict__ genc, int N) {
  __shared__ float sv[192];
  const int tid = threadIdx.x;
  if (tid < 192) sv[tid] = vav[tid];
  __syncthreads();
  const int n = blockIdx.x * 256 + tid;
  float pl = 0.f, pr = 0.f, py = 0.f;
  if (n < N) {
    const ushort* row = hb + ((size_t)n << 6);
#pragma unroll
    for (int q = 0; q < 8; ++q) {
      const uint4 raw = *(const uint4*)(row + (q << 3));
      float v[8];
      unpack8(raw, v);
#pragma unroll
      for (int j = 0; j < 8; ++j) {
        pl = fmaf(v[j], sv[q * 8 + j], pl);
        pr = fmaf(v[j], sv[64 + q * 8 + j], pr);
        py = fmaf(v[j], sv[128 + q * 8 + j], py);
      }
    }
    ely[n] = make_float2(pl, py);
    er[n] = pr;
  }
  float mx = (n < N) ? pl : -1e30f;
#pragma unroll
  for (int off = 32; off > 0; off >>= 1) mx = fmaxf(mx, __shfl_xor(mx, off));
  if ((tid & 63) == 0) atomicMax(genc, enc_f32(mx));
}

// ===== scalar GAT aggregation + pooling, 16 lanes/node =====
#define GSC_NPG 2
#define GSC_NPB (16 * GSC_NPG)
__global__ __launch_bounds__(256) void gat_scalar(
    const float2* __restrict__ ely, const float* __restrict__ er,
    const int* __restrict__ rowptr, const int* __restrict__ srcet,
    const unsigned* __restrict__ genc, const int* __restrict__ gids,
    float* __restrict__ out, int N, int B) {
  __shared__ float acc[256];
  for (int i = threadIdx.x; i < B; i += 256) acc[i] = 0.f;
  __syncthreads();
  const int grp = threadIdx.x >> 4;
  const int ln = threadIdx.x & 15;
  const float gmax = dec_f32(*genc);
  const int base = blockIdx.x * GSC_NPB + grp * GSC_NPG;

#pragma unroll
  for (int i = 0; i < GSC_NPG; ++i) {
    const int n = base + i;
    if (n < N) {
      const int beg = rowptr[n], end = rowptr[n + 1];
      const float ern = er[n];
      float mb = gmax + ern;
      mb = (mb > 0.f) ? mb : 0.2f * mb;
      float num = 0.f, den = 0.f;
      for (int j = beg + ln; j < end; j += 16) {
        const float2 e2 = ely[srcet[j] >> 8];  // {el, y} one 8B gather
        float x = e2.x + ern;
        x = (x > 0.f) ? x : 0.2f * x;
        const float w = __expf(x - mb);
        num = fmaf(w, e2.y, num);
        den += w;
      }
#pragma unroll
      for (int off = 1; off < 16; off <<= 1) {
        num += __shfl_xor(num, off);
        den += __shfl_xor(den, off);
      }
      if (ln == 0) atomicAdd(&acc[gids[n]], num / fmaxf(den, 1e-9f));
    }
  }
  __syncthreads();
  for (int i = threadIdx.x; i < B; i += 256) {
    const float v = acc[i];
    if (v != 0.f) unsafeAtomicAdd(out + i, v);
  }
}

// ================= launch =================
extern "C" void kernel_launch(void* const* d_in, const int* in_sizes, int n_in,
                              void* d_out, int out_size, void* d_ws,
                              size_t ws_size, hipStream_t stream) {
  const float* h0 = (const float*)d_in[0];
  const float* Wrel = (const float*)d_in[1];
  const float* Wloop = (const float*)d_in[2];
  const float* brel = (const float*)d_in[3];
  const float* Wg = (const float*)d_in[4];
  const float* al = (const float*)d_in[5];
  const float* ar = (const float*)d_in[6];
  const float* Wd = (const float*)d_in[7];
  const float* bd = (const float*)d_in[8];
  const int* src = (const int*)d_in[9];
  const int* dst = (const int*)d_in[10];
  const int* et = (const int*)d_in[11];
  const int* gids = (const int*)d_in[12];

  const int N = in_sizes[0] / DD;
  const int E = in_sizes[9];
  const int L = in_sizes[2] / (DD * DD);
  float* out = (float*)d_out;
  const int CAP8 = ((E / (256 * NREP)) * 2 + 63) & ~63;
  const int CAP = CAP8 * NREP;

  // ---- workspace layout ----
  char* wsb = (char*)d_ws;
  ushort* hbA = (ushort*)wsb;                    // N*64 bf16
  ushort* hbB = hbA + (size_t)N * DD;            // N*64 bf16
  ushort* aggr_bf = hbB + (size_t)N * DD;        // N*256 bf16 (25.6MB region)
  int* rowptr = (int*)(aggr_bf + (size_t)N * 256);  // N+1
  int* srcet = rowptr + N + 1;                   // E
  float2* ely = (float2*)(srcet + E);            // N float2 {el,y}
  float* er = (float*)(ely + N);                 // N
  int* gcur = (int*)(er + N);                    // 256*NREP
  unsigned* genc = (unsigned*)(gcur + 256 * NREP);  // 1
  unsigned* staging = (unsigned*)aggr_bf;        // 256*CAP uints
  float* vav = (float*)(genc + 1);               // 192 floats (va|vr|vd)
  // packed W (L*20480 bf16 = 160KB) overlaps ely: ely is dead until gat_proj,
  // which runs after the last dense layer (the last consumer of wpk).
  ushort* wpk = (ushort*)(((size_t)(char*)ely + 15) & ~(size_t)15);

  dim3 b256(256);
  const int grid_dense = (N + 63) / 64;
  const int nfb = (E + EPB - 1) / EPB;
  const int ncb = (N + 255) >> 8;
  const int n4 = N * DD / 4;
  const int ncv = (n4 + 255) / 256;

  // ---- weight packing + GAT vectors + init (block L+1) ----
  hipLaunchKernelGGL(pack_w, dim3(L + 2), b256, 0, stream, Wrel, Wloop, Wg, al,
                     ar, Wd, wpk, vav, L, out, bd, out_size, genc, gcur, CAP,
                     CAP8, rowptr, N, E);

  // ---- CSR build (+ appended conv blocks: h0 -> bf16); cscan2 folded ----
  hipLaunchKernelGGL(f2_coarse, dim3(nfb + ncv), b256, 0, stream, src, dst, et,
                     gcur, staging, E, nfb, h0, hbA, n4);
  hipLaunchKernelGGL(f3_fine4, dim3(ncb * 4), b256, 0, stream, staging, gcur,
                     rowptr, srcet, N, CAP, CAP8);

  // ---- RGCN layers (proven r3 gather + MFMA dense) ----
  ushort* cur = hbA;
  ushort* nxt = hbB;
  const int grid_g = (N + 3) / 4;
  for (int l = 0; l < L; ++l) {
    hipLaunchKernelGGL(gather_rel, dim3(grid_g), b256, 0, stream, cur, rowptr,
                       srcet, aggr_bf, N);
    hipLaunchKernelGGL(rgcn_dense_mfma, dim3(grid_dense), b256, 0, stream,
                       aggr_bf, cur, wpk + (size_t)l * 20480,
                       brel + (size_t)l * DD, nxt, N);
    ushort* tmp = cur; cur = nxt; nxt = tmp;
  }

  // ---- GAT: fused projection, then scalar aggregation + pooling ----
  hipLaunchKernelGGL(gat_proj, dim3((N + 255) / 256), b256, 0, stream, cur, vav,
                     ely, er, genc, N);
  const int grid_gs = (N + GSC_NPB - 1) / GSC_NPB;
  hipLaunchKernelGGL(gat_scalar, dim3(grid_gs), b256, 0, stream, ely, er,
                     rowptr, srcet, genc, gids, out, N, out_size);
}